// Round 10
// baseline (294.175 us; speedup 1.0000x reference)
//
#include <hip/hip_runtime.h>
#include <hip/hip_bf16.h>
#include <math.h>

// MPN-COV: cov = (X X^T - S S^T/N)/(N-1); sqrt via coupled Newton-Schulz
// (3 iters, trace-normalized, Z0=I shortcut); triu-pack fused into final NS
// epilogue.  B=64, C=256, N=4096.  ws ~= 1 GiB.
// Round 10: gram granule fix — HBM was delivering ~1 TB/s on 256-B gathered
// granules. Now: k-chunk 128 (512 B/row), single 128-KB LDS buffer,
// REGISTER prefetch (16 coalesced dwordx4/thread) instead of LDS dbuf;
// row sums from prefetch regs. 512 thr, 8 waves of 64x128, acc in AGPRs.

#define B_ 64
#define C_ 256
#define N_ 4096
#define TRI ((C_*(C_+1))/2)
#define MATE (C_*C_)
#define TOTE ((size_t)B_*MATE)
#define KS 4
#define KW (N_/KS)              // 1024

typedef __attribute__((ext_vector_type(8))) short bf16x8;
typedef __attribute__((ext_vector_type(4))) short short4v;
typedef __attribute__((ext_vector_type(4))) float f32x4;

__device__ __forceinline__ short f2bf(float f) {        // RNE float->bf16
    unsigned u = __float_as_uint(f);
    return (short)((u + 0x7FFFu + ((u >> 16) & 1u)) >> 16);
}
__device__ __forceinline__ float bf2f(short s) {
    return __uint_as_float(((unsigned)(unsigned short)s) << 16);
}
__device__ __forceinline__ void gload_lds16(const void* g, void* l) {
    __builtin_amdgcn_global_load_lds(
        (const __attribute__((address_space(1))) void*)g,
        (__attribute__((address_space(3))) void*)l, 16, 0, 0);
}
// native convert (compiler emits v_cvt_pk_bf16_f32; RNE)
__device__ __forceinline__ bf16x8 cvt8n(f32x4 u, f32x4 v) {
    bf16x8 r;
    #pragma unroll
    for (int e = 0; e < 4; ++e) {
        __hip_bfloat16 a = __float2bfloat16(u[e]);
        __hip_bfloat16 b = __float2bfloat16(v[e]);
        r[e]     = *reinterpret_cast<short*>(&a);
        r[4 + e] = *reinterpret_cast<short*>(&b);
    }
    return r;
}

// ================= gram partials (256x256 tile, K-slab 1024) ================
// grid 256 = 64 batches x 4 slabs; 512 threads = 8 waves (4x2), wave does
// 64x128 (acc 128 AGPR). Per step: regs hold fp32 chunk c (128 k/row);
// ds_write to swizzled LDS; issue coalesced prefetch of c+1 into regs;
// compute (frag read fp32 -> cvt bf16 -> MFMA). Row sums from prefetch regs.
__global__ __launch_bounds__(512) void gram_cov(const float* __restrict__ x,
                                                short* __restrict__ Gp,
                                                float* __restrict__ Sp) {
    int bid = (blockIdx.x & 7) * 32 + (blockIdx.x >> 3);   // XCD swizzle (256)
    int b = bid >> 2, slab = bid & 3;
    const char* xb = (const char*)(x + (size_t)b * C_ * N_ + (size_t)slab * KW);

    __shared__ float Xs[32768];         // 128 KB: [256 rows][128 k fp32], swz

    int tid = threadIdx.x;
    int lane = tid & 63, wid = tid >> 6;
    int wr = wid >> 1, wc = wid & 1;    // 4 x 2 wave grid, tile 64 x 128
    int lr = lane & 15, hi = lane >> 4;
    unsigned swz = (unsigned)((lane & 7) << 4);   // row&7 == lane&7 for frags

    f32x4 acc[4][8] = {};
    f32x4 pf[16];
    float ps[16] = {};

    // prefetch chunk 0 (fully coalesced: per instr, 2 rows x 512 B segments)
    #pragma unroll
    for (int i = 0; i < 16; ++i) {
        int U = i * 512 + tid;
        int row = U >> 5, kb = (U & 31) * 16;
        pf[i] = *(const f32x4*)(xb + (size_t)row * (N_ * 4) + kb);
    }

    const int NSTEP = KW / 128;         // 8
    for (int c = 0; c < NSTEP; ++c) {
        if (c) __syncthreads();         // all waves done reading LDS chunk c-1
        // write chunk c regs -> LDS (swizzled), fold row-sum partials
        #pragma unroll
        for (int i = 0; i < 16; ++i) {
            int U = i * 512 + tid;
            int row = U >> 5, kb = (U & 31) * 16;
            ps[i] += pf[i][0] + pf[i][1] + pf[i][2] + pf[i][3];
            *(f32x4*)((char*)Xs + row * 512 + (kb ^ ((row & 7) << 4))) = pf[i];
        }
        __syncthreads();
        // issue prefetch of chunk c+1 (drains at next iteration's ds_write)
        if (c + 1 < NSTEP) {
            #pragma unroll
            for (int i = 0; i < 16; ++i) {
                int U = i * 512 + tid;
                int row = U >> 5, kb = (U & 31) * 16;
                pf[i] = *(const f32x4*)(xb + (size_t)row * (N_ * 4) +
                                        (c + 1) * 512 + kb);
            }
        }
        // compute chunk c: 4 x 32-k sub-chunks
        #pragma unroll
        for (int c2 = 0; c2 < 4; ++c2) {
            unsigned o1 = ((unsigned)(c2 * 128 + hi * 32)) ^ swz;
            bf16x8 af[4];
            #pragma unroll
            for (int m = 0; m < 4; ++m) {
                const char* base = (const char*)Xs + (wr * 64 + m * 16 + lr) * 512;
                f32x4 u = *(const f32x4*)(base + o1);
                f32x4 v = *(const f32x4*)(base + (o1 ^ 16u));
                af[m] = cvt8n(u, v);
            }
            #pragma unroll
            for (int n = 0; n < 8; ++n) {
                const char* base = (const char*)Xs + (wc * 128 + n * 16 + lr) * 512;
                f32x4 u = *(const f32x4*)(base + o1);
                f32x4 v = *(const f32x4*)(base + (o1 ^ 16u));
                bf16x8 bb = cvt8n(u, v);
                #pragma unroll
                for (int m = 0; m < 4; ++m)
                    acc[m][n] = __builtin_amdgcn_mfma_f32_16x16x32_bf16(af[m], bb, acc[m][n], 0, 0, 0);
            }
        }
    }

    // row sums: accumulator i covers row i*16 + (tid>>5); reduce 32-lane group
    #pragma unroll
    for (int i = 0; i < 16; ++i) {
        float s = ps[i];
        s += __shfl_down(s, 16, 32);
        s += __shfl_down(s, 8, 32);
        s += __shfl_down(s, 4, 32);
        s += __shfl_down(s, 2, 32);
        s += __shfl_down(s, 1, 32);
        if ((tid & 31) == 0)
            Sp[((size_t)slab * B_ + b) * C_ + i * 16 + (tid >> 5)] = s;
    }

    // partial gram -> bf16
    short* G = Gp + ((size_t)slab * B_ + b) * MATE;
    #pragma unroll
    for (int m = 0; m < 4; ++m)
        #pragma unroll
        for (int n = 0; n < 8; ++n)
            #pragma unroll
            for (int r = 0; r < 4; ++r) {
                int i = wr * 64 + m * 16 + hi * 4 + r;
                int j = wc * 128 + n * 16 + lr;
                G[(size_t)i * C_ + j] = f2bf(acc[m][n][r]);
            }
}

// ========== trace: S totals + m = tr(cov)/C, 1/m, sqrt(m) per batch ==========
__global__ __launch_bounds__(256) void trace_kernel(const short* __restrict__ Gp,
                                                    const float* __restrict__ Sp,
                                                    float* __restrict__ S,
                                                    float* __restrict__ mArr) {
    int b = blockIdx.x, i = threadIdx.x;
    float s = 0.f, g = 0.f;
    #pragma unroll
    for (int sl = 0; sl < KS; ++sl) {
        s += Sp[((size_t)sl * B_ + b) * C_ + i];
        g += bf2f(Gp[((size_t)sl * B_ + b) * MATE + (size_t)i * (C_ + 1)]);
    }
    S[b * C_ + i] = s;
    float c = (g - s * s * (1.0f / N_)) * (1.0f / (N_ - 1));
    __shared__ float red[256];
    red[i] = c;
    __syncthreads();
    for (int off = 128; off; off >>= 1) {
        if (i < off) red[i] += red[i + off];
        __syncthreads();
    }
    if (i == 0) {
        float m = red[0] * (1.0f / C_);
        mArr[b] = m;
        mArr[64 + b] = 1.0f / m;
        mArr[128 + b] = sqrtf(m);
    }
}

// == init: cov from partials, Y0 = cov/m (bf16), Z1 = 1.5I - 0.5*Y0 (bf16) ==
__global__ __launch_bounds__(256) void init_kernel(const short* __restrict__ Gp,
                                                   const float* __restrict__ S,
                                                   const float* __restrict__ mArr,
                                                   short* __restrict__ Y0,
                                                   short* __restrict__ Z1) {
    int idx = blockIdx.x * 256 + threadIdx.x;
    size_t e0 = (size_t)idx * 8;                // 8 elems / thread (16B)
    int b = (int)(e0 >> 16);
    int ij = (int)(e0 & 65535);
    int i = ij >> 8, j0 = ij & 255;
    float g[8] = {};
    #pragma unroll
    for (int sl = 0; sl < KS; ++sl) {
        bf16x8 t = *(const bf16x8*)(Gp + (size_t)sl * TOTE + e0);
        #pragma unroll
        for (int q = 0; q < 8; ++q) g[q] += bf2f(t[q]);
    }
    float Si = S[b * C_ + i];
    f32x4 sjA = *(const f32x4*)(S + b * C_ + j0);
    f32x4 sjB = *(const f32x4*)(S + b * C_ + j0 + 4);
    float invm = mArr[64 + b];
    const float invN = 1.0f / (float)N_;
    const float invN1 = 1.0f / (float)(N_ - 1);
    bf16x8 y, z;
    #pragma unroll
    for (int q = 0; q < 8; ++q) {
        float sj = (q < 4) ? sjA[q] : sjB[q - 4];
        float cov = (g[q] - Si * sj * invN) * invN1;
        float a = cov * invm;
        y[q] = f2bf(a);
        z[q] = f2bf(((i == j0 + q) ? 1.5f : 0.0f) - 0.5f * a);
    }
    *(bf16x8*)(Y0 + e0) = y;
    *(bf16x8*)(Z1 + e0) = z;
}

// ================= NS GEMM (K=256 in 2 staged halves, 64 KB LDS) =============
// acc[i,j] = sum_k A[i,k]*B[j,k]  (all iterates symmetric -> NT form)
// EP: 0 = P bf16 (acc); 1 = YZ' bf16 (1.5*Base - 0.5*acc), optional dual;
//     2 = final: out[b, triu(i,j)] = sqrt(m)*(1.5*Base - 0.5*acc), upper tiles
template<int EP, bool DUAL>
__global__ __launch_bounds__(256) void ns_gemm(
        const short* A0, const short* B0, const short* Ba0, void* C0,
        const short* A1, const short* B1, const short* Ba1, void* C1,
        const float* __restrict__ mArr) {
    int nb = gridDim.x, per = nb >> 3;
    int bid = (blockIdx.x & 7) * per + (blockIdx.x >> 3);  // XCD swizzle
    const short *A = A0, *B = B0, *Ba = Ba0; void* C = C0;
    if (DUAL && bid >= (nb >> 1)) { bid -= nb >> 1; A = A1; B = B1; Ba = Ba1; C = C1; }
    int b, ti, tj;
    if constexpr (EP == 2) {
        b = bid / 3; int t = bid % 3;
        ti = (t == 2) ? 1 : 0; tj = (t == 0) ? 0 : 1;     // (0,0),(0,1),(1,1)
    } else {
        b = bid >> 2; int t = bid & 3;
        ti = t >> 1; tj = t & 1;
    }
    const short* Ap = A + (size_t)b * MATE + (size_t)ti * 128 * C_;
    const short* Bp = B + (size_t)b * MATE + (size_t)tj * 128 * C_;

    __shared__ short As[16384], Bs[16384];   // 32 KB each: [128 rows][128 k]

    int tid = threadIdx.x, lane = tid & 63, wid = tid >> 6;
    int wr = wid >> 1, wc = wid & 1;
    int lr = lane & 15, hi = lane >> 4;
    f32x4 acc[4][4] = {};

    for (int h = 0; h < 2; ++h) {
        // stage half h: linear LDS dest, inverse-swizzled source (rule #21)
        #pragma unroll
        for (int q = 0; q < 8; ++q) {
            int d = (q * 256 + tid) * 16;
            int row = d >> 8;
            int inner = (d & 255) ^ ((row & 7) << 4);
            gload_lds16((const char*)Ap + (size_t)row * 512 + h * 256 + inner,
                        (char*)As + d);
            gload_lds16((const char*)Bp + (size_t)row * 512 + h * 256 + inner,
                        (char*)Bs + d);
        }
        __syncthreads();
        #pragma unroll
        for (int ks = 0; ks < 4; ++ks) {
            bf16x8 af[4], bb[4];
            #pragma unroll
            for (int m = 0; m < 4; ++m) {
                int rowa = wr * 64 + m * 16 + lr;
                af[m] = *(const bf16x8*)((const char*)As + rowa * 256 +
                                         ((ks * 64 + hi * 16) ^ ((rowa & 7) << 4)));
                int rowb = wc * 64 + m * 16 + lr;
                bb[m] = *(const bf16x8*)((const char*)Bs + rowb * 256 +
                                         ((ks * 64 + hi * 16) ^ ((rowb & 7) << 4)));
            }
            #pragma unroll
            for (int m = 0; m < 4; ++m)
                #pragma unroll
                for (int n = 0; n < 4; ++n)
                    acc[m][n] = __builtin_amdgcn_mfma_f32_16x16x32_bf16(af[m], bb[n], acc[m][n], 0, 0, 0);
        }
        if (h == 0) __syncthreads();   // buffer reuse for half 1
    }

    int r0 = hi * 4;
    float sqm = (EP == 2) ? mArr[128 + b] : 0.f;
    #pragma unroll
    for (int m = 0; m < 4; ++m)
        #pragma unroll
        for (int n = 0; n < 4; ++n)
            #pragma unroll
            for (int r = 0; r < 4; ++r) {
                int i = ti * 128 + wr * 64 + m * 16 + r0 + r;
                int j = tj * 128 + wc * 64 + n * 16 + lr;
                size_t idx = (size_t)b * MATE + (size_t)i * C_ + j;
                float v = acc[m][n][r];
                if constexpr (EP == 0) {
                    ((short*)C)[idx] = f2bf(v);
                } else if constexpr (EP == 1) {
                    ((short*)C)[idx] = f2bf(1.5f * bf2f(Ba[idx]) - 0.5f * v);
                } else {
                    if (j >= i) {
                        size_t o = (size_t)b * TRI + (size_t)i * C_ - (size_t)(i * (i - 1)) / 2 + (j - i);
                        ((float*)C)[o] = sqm * (1.5f * bf2f(Ba[idx]) - 0.5f * v);
                    }
                }
            }
}

extern "C" void kernel_launch(void* const* d_in, const int* in_sizes, int n_in,
                              void* d_out, int out_size, void* d_ws, size_t ws_size,
                              hipStream_t stream) {
    const float* x = (const float*)d_in[0];
    float* out = (float*)d_out;

    float* mArr = (float*)d_ws;                    // 256 floats (m, 1/m, sqrt m)
    float* S    = mArr + 256;                      // 16384
    float* Sp   = S + 16384;                       // KS*B*C = 65536
    short* Gp   = (short*)(Sp + (size_t)KS * B_ * C_);   // KS*TOTE bf16 = 32MB
    short* bufs = Gp + (size_t)KS * TOTE;
    short* M0 = bufs;                              // 5 bf16 matrices, 8MB each
    short* M1 = bufs + TOTE;
    short* M2 = bufs + 2 * TOTE;
    short* M3 = bufs + 3 * TOTE;
    short* M4 = bufs + 4 * TOTE;

    // gram partials (bf16) + row-sum partials
    gram_cov<<<B_ * KS, 512, 0, stream>>>(x, Gp, Sp);
    // per-batch trace -> m, 1/m, sqrt(m); total row sums
    trace_kernel<<<B_, 256, 0, stream>>>(Gp, Sp, S, mArr);
    // cov assembly: Y0 -> M0, Z1 = 1.5I - 0.5*Y0 -> M1
    init_kernel<<<(int)(TOTE / 8 / 256), 256, 0, stream>>>(Gp, S, mArr, M0, M1);

    // it1 (Z0=I): Y1 = 1.5*Y0 - 0.5*Y0*Y0 -> M2
    ns_gemm<1, false><<<256, 256, 0, stream>>>(M0, M0, M0, M2,
                                               nullptr, nullptr, nullptr, nullptr, nullptr);
    // it2: P1 = Z1*Y1 -> M3
    ns_gemm<0, false><<<256, 256, 0, stream>>>(M1, M2, nullptr, M3,
                                               nullptr, nullptr, nullptr, nullptr, nullptr);
    //      Y2 = 1.5Y1 - 0.5*Y1*P1 -> M4 || Z2 = 1.5Z1 - 0.5*P1*Z1 -> M0
    ns_gemm<1, true><<<512, 256, 0, stream>>>(M2, M3, M2, M4,
                                              M3, M1, M1, M0, nullptr);
    // it3: P2 = Z2*Y2 -> M2
    ns_gemm<0, false><<<256, 256, 0, stream>>>(M0, M4, nullptr, M2,
                                               nullptr, nullptr, nullptr, nullptr, nullptr);
    //      final: out = sqrt(m)*(1.5Y2 - 0.5*Y2*P2), triu-packed, upper tiles
    ns_gemm<2, false><<<B_ * 3, 256, 0, stream>>>(M4, M2, M4, out,
                                                  nullptr, nullptr, nullptr, nullptr, mArr);
}

// Round 11
// 194.355 us; speedup vs baseline: 1.5136x; 1.5136x over previous
//
#include <hip/hip_runtime.h>
#include <hip/hip_bf16.h>
#include <math.h>

// MPN-COV: cov = (X X^T - S S^T/N)/(N-1); sqrt via coupled Newton-Schulz
// (3 iters, trace-normalized, Z0=I shortcut); triu-pack fused into final NS
// epilogue.  B=64, C=256, N=4096.  ws ~= 1 GiB.
// Round 11: two-pass gram. Pass 1: streaming fp32->bf16 convert + exact row
// sums (granule-sensitive x-read now perfectly coalesced). Pass 2: gram from
// bf16 (L3-resident), DMA-staged (reg-safe; rounds 6/10 proved reg-staging
// spills), no cvt in the MFMA loop. NS chain unchanged (round-9 proven).

#define B_ 64
#define C_ 256
#define N_ 4096
#define TRI ((C_*(C_+1))/2)
#define MATE (C_*C_)
#define TOTE ((size_t)B_*MATE)
#define KS 4
#define KW (N_/KS)              // 1024

typedef __attribute__((ext_vector_type(8))) short bf16x8;
typedef __attribute__((ext_vector_type(4))) short short4v;
typedef __attribute__((ext_vector_type(4))) float f32x4;

__device__ __forceinline__ short f2bf(float f) {        // RNE float->bf16
    unsigned u = __float_as_uint(f);
    return (short)((u + 0x7FFFu + ((u >> 16) & 1u)) >> 16);
}
__device__ __forceinline__ float bf2f(short s) {
    return __uint_as_float(((unsigned)(unsigned short)s) << 16);
}
__device__ __forceinline__ void gload_lds16(const void* g, void* l) {
    __builtin_amdgcn_global_load_lds(
        (const __attribute__((address_space(1))) void*)g,
        (__attribute__((address_space(3))) void*)l, 16, 0, 0);
}
// opaque 16B LDS read (bf16x8): waitcnt pass can't pessimize (rule #18)
__device__ __forceinline__ bf16x8 ds_read16s(unsigned addr) {
    bf16x8 r;
    asm volatile("ds_read_b128 %0, %1" : "=v"(r) : "v"(addr));
    return r;
}
__device__ __forceinline__ void lgkm0_fence() {
    asm volatile("s_waitcnt lgkmcnt(0)" ::: "memory");
    __builtin_amdgcn_sched_barrier(0);
}

// ========== pass 1: fp32 -> bf16 convert + exact per-row sums ==========
// one block per (b,c) row; 256 thr; read 16 KB, write 8 KB, fully coalesced.
__global__ __launch_bounds__(256) void convert_sums(const float* __restrict__ x,
                                                    short* __restrict__ xb,
                                                    float* __restrict__ S) {
    int row = blockIdx.x;                       // b*C + c
    const float* p = x + (size_t)row * N_;
    short* q = xb + (size_t)row * N_;
    int tid = threadIdx.x;
    float s = 0.f;
    #pragma unroll
    for (int i = 0; i < 2; ++i) {
        int e = (tid + i * 256) * 8;            // 8 floats / unit
        f32x4 u = *(const f32x4*)(p + e);
        f32x4 v = *(const f32x4*)(p + e + 4);
        s += u[0] + u[1] + u[2] + u[3] + v[0] + v[1] + v[2] + v[3];
        bf16x8 o;
        #pragma unroll
        for (int k = 0; k < 4; ++k) { o[k] = f2bf(u[k]); o[4 + k] = f2bf(v[k]); }
        *(bf16x8*)(q + e) = o;
    }
    for (int off = 32; off; off >>= 1) s += __shfl_down(s, off);
    __shared__ float red[4];
    if ((tid & 63) == 0) red[tid >> 6] = s;
    __syncthreads();
    if (tid == 0) S[row] = red[0] + red[1] + red[2] + red[3];
}

// ================= gram partials (256x256 tile, K-slab 1024, bf16) ==========
// grid 256 = 64 batches x 4 slabs; 1024 thr = 16 waves (4x4), wave 64x64
// (acc 64 regs, frags 32 -> fits 128-VGPR cap). bf16 slab staged via
// global_load_lds, 128-k steps (64 KB), dbuf 2x64KB. No cvt in loop.
__global__ __launch_bounds__(1024) void gram_cov(const short* __restrict__ xb,
                                                 short* __restrict__ Gp) {
    int bid = (blockIdx.x & 7) * 32 + (blockIdx.x >> 3);   // XCD swizzle (256)
    int b = bid >> 2, slab = bid & 3;
    const char* xs = (const char*)(xb + (size_t)b * C_ * N_ + (size_t)slab * KW);

    __shared__ short Xs[2][32768];      // 2 x [256 rows][128 k bf16], swizzled

    int tid = threadIdx.x;
    int lane = tid & 63, wid = tid >> 6;
    int wr = wid >> 2, wc = wid & 3;    // 4 x 4 wave grid, tile 64 x 64
    int lr = lane & 15, hi = lane >> 4;

    unsigned xs0 = (unsigned)(unsigned long long)
        (__attribute__((address_space(3))) char*)&Xs[0][0];
    unsigned swz = (unsigned)((lr & 7) << 4);
    unsigned rowA = (unsigned)((wr * 64 + lr) * 256);   // byte row base
    unsigned rowB = (unsigned)((wc * 64 + lr) * 256);

    f32x4 acc[4][4] = {};

    // stage chunk 0: linear LDS dest, inverse-swizzled source (rule #21)
    #pragma unroll
    for (int q = 0; q < 4; ++q) {
        int d = (q * 1024 + tid) * 16;
        int row = d >> 8;                       // 256 B per row (128 k bf16)
        int inner = (d & 255) ^ ((row & 7) << 4);
        gload_lds16(xs + (size_t)row * (N_ * 2) + inner, (char*)Xs[0] + d);
    }
    __syncthreads();

    const int NSTEP = KW / 128;         // 8
    for (int c = 0; c < NSTEP; ++c) {
        // issue next chunk's staging; stays in flight under compute
        if (c + 1 < NSTEP) {
            #pragma unroll
            for (int q = 0; q < 4; ++q) {
                int d = (q * 1024 + tid) * 16;
                int row = d >> 8;
                int inner = (d & 255) ^ ((row & 7) << 4);
                gload_lds16(xs + (size_t)row * (N_ * 2) + (c + 1) * 256 + inner,
                            (char*)Xs[(c + 1) & 1] + d);
            }
        }
        unsigned xsb = xs0 + (unsigned)((c & 1) * 65536);
        #pragma unroll
        for (int ks2 = 0; ks2 < 4; ++ks2) {     // 4 x 32-k sub-chunks
            unsigned o1 = ((unsigned)(ks2 * 64 + hi * 16)) ^ swz;
            bf16x8 af[4], bb[4];
            #pragma unroll
            for (int m = 0; m < 4; ++m)
                af[m] = ds_read16s(xsb + rowA + (unsigned)(m * 4096) + o1);
            #pragma unroll
            for (int n = 0; n < 4; ++n)
                bb[n] = ds_read16s(xsb + rowB + (unsigned)(n * 4096) + o1);
            lgkm0_fence();
            #pragma unroll
            for (int m = 0; m < 4; ++m)
                #pragma unroll
                for (int n = 0; n < 4; ++n)
                    acc[m][n] = __builtin_amdgcn_mfma_f32_16x16x32_bf16(af[m], bb[n], acc[m][n], 0, 0, 0);
        }
        __syncthreads();   // drains vmcnt (chunk c+1) + LDS reuse hazard
    }

    // partial gram -> bf16
    short* G = Gp + ((size_t)slab * B_ + b) * MATE;
    #pragma unroll
    for (int m = 0; m < 4; ++m)
        #pragma unroll
        for (int n = 0; n < 4; ++n)
            #pragma unroll
            for (int r = 0; r < 4; ++r) {
                int i = wr * 64 + m * 16 + hi * 4 + r;
                int j = wc * 64 + n * 16 + lr;
                G[(size_t)i * C_ + j] = f2bf(acc[m][n][r]);
            }
}

// ========== trace: m = tr(cov)/C, 1/m, sqrt(m) per batch ==========
__global__ __launch_bounds__(256) void trace_kernel(const short* __restrict__ Gp,
                                                    const float* __restrict__ S,
                                                    float* __restrict__ mArr) {
    int b = blockIdx.x, i = threadIdx.x;
    float s = S[b * C_ + i], g = 0.f;
    #pragma unroll
    for (int sl = 0; sl < KS; ++sl)
        g += bf2f(Gp[((size_t)sl * B_ + b) * MATE + (size_t)i * (C_ + 1)]);
    float c = (g - s * s * (1.0f / N_)) * (1.0f / (N_ - 1));
    __shared__ float red[256];
    red[i] = c;
    __syncthreads();
    for (int off = 128; off; off >>= 1) {
        if (i < off) red[i] += red[i + off];
        __syncthreads();
    }
    if (i == 0) {
        float m = red[0] * (1.0f / C_);
        mArr[b] = m;
        mArr[64 + b] = 1.0f / m;
        mArr[128 + b] = sqrtf(m);
    }
}

// == init: cov from partials, Y0 = cov/m (bf16), Z1 = 1.5I - 0.5*Y0 (bf16) ==
__global__ __launch_bounds__(256) void init_kernel(const short* __restrict__ Gp,
                                                   const float* __restrict__ S,
                                                   const float* __restrict__ mArr,
                                                   short* __restrict__ Y0,
                                                   short* __restrict__ Z1) {
    int idx = blockIdx.x * 256 + threadIdx.x;
    size_t e0 = (size_t)idx * 8;                // 8 elems / thread (16B)
    int b = (int)(e0 >> 16);
    int ij = (int)(e0 & 65535);
    int i = ij >> 8, j0 = ij & 255;
    float g[8] = {};
    #pragma unroll
    for (int sl = 0; sl < KS; ++sl) {
        bf16x8 t = *(const bf16x8*)(Gp + (size_t)sl * TOTE + e0);
        #pragma unroll
        for (int q = 0; q < 8; ++q) g[q] += bf2f(t[q]);
    }
    float Si = S[b * C_ + i];
    f32x4 sjA = *(const f32x4*)(S + b * C_ + j0);
    f32x4 sjB = *(const f32x4*)(S + b * C_ + j0 + 4);
    float invm = mArr[64 + b];
    const float invN = 1.0f / (float)N_;
    const float invN1 = 1.0f / (float)(N_ - 1);
    bf16x8 y, z;
    #pragma unroll
    for (int q = 0; q < 8; ++q) {
        float sj = (q < 4) ? sjA[q] : sjB[q - 4];
        float cov = (g[q] - Si * sj * invN) * invN1;
        float a = cov * invm;
        y[q] = f2bf(a);
        z[q] = f2bf(((i == j0 + q) ? 1.5f : 0.0f) - 0.5f * a);
    }
    *(bf16x8*)(Y0 + e0) = y;
    *(bf16x8*)(Z1 + e0) = z;
}

// ================= NS GEMM (K=256 in 2 staged halves, 64 KB LDS) =============
// acc[i,j] = sum_k A[i,k]*B[j,k]  (all iterates symmetric -> NT form)
// EP: 0 = P bf16 (acc); 1 = YZ' bf16 (1.5*Base - 0.5*acc), optional dual;
//     2 = final: out[b, triu(i,j)] = sqrt(m)*(1.5*Base - 0.5*acc), upper tiles
template<int EP, bool DUAL>
__global__ __launch_bounds__(256) void ns_gemm(
        const short* A0, const short* B0, const short* Ba0, void* C0,
        const short* A1, const short* B1, const short* Ba1, void* C1,
        const float* __restrict__ mArr) {
    int nb = gridDim.x, per = nb >> 3;
    int bid = (blockIdx.x & 7) * per + (blockIdx.x >> 3);  // XCD swizzle
    const short *A = A0, *B = B0, *Ba = Ba0; void* C = C0;
    if (DUAL && bid >= (nb >> 1)) { bid -= nb >> 1; A = A1; B = B1; Ba = Ba1; C = C1; }
    int b, ti, tj;
    if constexpr (EP == 2) {
        b = bid / 3; int t = bid % 3;
        ti = (t == 2) ? 1 : 0; tj = (t == 0) ? 0 : 1;     // (0,0),(0,1),(1,1)
    } else {
        b = bid >> 2; int t = bid & 3;
        ti = t >> 1; tj = t & 1;
    }
    const short* Ap = A + (size_t)b * MATE + (size_t)ti * 128 * C_;
    const short* Bp = B + (size_t)b * MATE + (size_t)tj * 128 * C_;

    __shared__ short As[16384], Bs[16384];   // 32 KB each: [128 rows][128 k]

    int tid = threadIdx.x, lane = tid & 63, wid = tid >> 6;
    int wr = wid >> 1, wc = wid & 1;
    int lr = lane & 15, hi = lane >> 4;
    f32x4 acc[4][4] = {};

    for (int h = 0; h < 2; ++h) {
        // stage half h: linear LDS dest, inverse-swizzled source (rule #21)
        #pragma unroll
        for (int q = 0; q < 8; ++q) {
            int d = (q * 256 + tid) * 16;
            int row = d >> 8;
            int inner = (d & 255) ^ ((row & 7) << 4);
            gload_lds16((const char*)Ap + (size_t)row * 512 + h * 256 + inner,
                        (char*)As + d);
            gload_lds16((const char*)Bp + (size_t)row * 512 + h * 256 + inner,
                        (char*)Bs + d);
        }
        __syncthreads();
        #pragma unroll
        for (int ks = 0; ks < 4; ++ks) {
            bf16x8 af[4], bb[4];
            #pragma unroll
            for (int m = 0; m < 4; ++m) {
                int rowa = wr * 64 + m * 16 + lr;
                af[m] = *(const bf16x8*)((const char*)As + rowa * 256 +
                                         ((ks * 64 + hi * 16) ^ ((rowa & 7) << 4)));
                int rowb = wc * 64 + m * 16 + lr;
                bb[m] = *(const bf16x8*)((const char*)Bs + rowb * 256 +
                                         ((ks * 64 + hi * 16) ^ ((rowb & 7) << 4)));
            }
            #pragma unroll
            for (int m = 0; m < 4; ++m)
                #pragma unroll
                for (int n = 0; n < 4; ++n)
                    acc[m][n] = __builtin_amdgcn_mfma_f32_16x16x32_bf16(af[m], bb[n], acc[m][n], 0, 0, 0);
        }
        if (h == 0) __syncthreads();   // buffer reuse for half 1
    }

    int r0 = hi * 4;
    float sqm = (EP == 2) ? mArr[128 + b] : 0.f;
    #pragma unroll
    for (int m = 0; m < 4; ++m)
        #pragma unroll
        for (int n = 0; n < 4; ++n)
            #pragma unroll
            for (int r = 0; r < 4; ++r) {
                int i = ti * 128 + wr * 64 + m * 16 + r0 + r;
                int j = tj * 128 + wc * 64 + n * 16 + lr;
                size_t idx = (size_t)b * MATE + (size_t)i * C_ + j;
                float v = acc[m][n][r];
                if constexpr (EP == 0) {
                    ((short*)C)[idx] = f2bf(v);
                } else if constexpr (EP == 1) {
                    ((short*)C)[idx] = f2bf(1.5f * bf2f(Ba[idx]) - 0.5f * v);
                } else {
                    if (j >= i) {
                        size_t o = (size_t)b * TRI + (size_t)i * C_ - (size_t)(i * (i - 1)) / 2 + (j - i);
                        ((float*)C)[o] = sqm * (1.5f * bf2f(Ba[idx]) - 0.5f * v);
                    }
                }
            }
}

extern "C" void kernel_launch(void* const* d_in, const int* in_sizes, int n_in,
                              void* d_out, int out_size, void* d_ws, size_t ws_size,
                              hipStream_t stream) {
    const float* x = (const float*)d_in[0];
    float* out = (float*)d_out;

    float* mArr = (float*)d_ws;                    // 256 floats (m, 1/m, sqrt m)
    float* S    = mArr + 256;                      // 16384 (exact row sums)
    short* Gp   = (short*)(S + 16384);             // KS*TOTE bf16 = 32MB
    short* xbuf = Gp + (size_t)KS * TOTE;          // bf16 x copy, 128 MB
    short* bufs = xbuf + (size_t)B_ * C_ * N_;
    short* M0 = bufs;                              // 5 bf16 matrices, 8MB each
    short* M1 = bufs + TOTE;
    short* M2 = bufs + 2 * TOTE;
    short* M3 = bufs + 3 * TOTE;
    short* M4 = bufs + 4 * TOTE;

    // pass 1: streaming fp32->bf16 + exact row sums
    convert_sums<<<B_ * C_, 256, 0, stream>>>(x, xbuf, S);
    // pass 2: gram partials (bf16, L3-fed)
    gram_cov<<<B_ * KS, 1024, 0, stream>>>(xbuf, Gp);
    // per-batch trace -> m, 1/m, sqrt(m)
    trace_kernel<<<B_, 256, 0, stream>>>(Gp, S, mArr);
    // cov assembly: Y0 -> M0, Z1 = 1.5I - 0.5*Y0 -> M1
    init_kernel<<<(int)(TOTE / 8 / 256), 256, 0, stream>>>(Gp, S, mArr, M0, M1);

    // it1 (Z0=I): Y1 = 1.5*Y0 - 0.5*Y0*Y0 -> M2
    ns_gemm<1, false><<<256, 256, 0, stream>>>(M0, M0, M0, M2,
                                               nullptr, nullptr, nullptr, nullptr, nullptr);
    // it2: P1 = Z1*Y1 -> M3
    ns_gemm<0, false><<<256, 256, 0, stream>>>(M1, M2, nullptr, M3,
                                               nullptr, nullptr, nullptr, nullptr, nullptr);
    //      Y2 = 1.5Y1 - 0.5*Y1*P1 -> M4 || Z2 = 1.5Z1 - 0.5*P1*Z1 -> M0
    ns_gemm<1, true><<<512, 256, 0, stream>>>(M2, M3, M2, M4,
                                              M3, M1, M1, M0, nullptr);
    // it3: P2 = Z2*Y2 -> M2
    ns_gemm<0, false><<<256, 256, 0, stream>>>(M0, M4, nullptr, M2,
                                               nullptr, nullptr, nullptr, nullptr, nullptr);
    //      final: out = sqrt(m)*(1.5Y2 - 0.5*Y2*P2), triu-packed, upper tiles
    ns_gemm<2, false><<<B_ * 3, 256, 0, stream>>>(M4, M2, M4, out,
                                                  nullptr, nullptr, nullptr, nullptr, mArr);
}